// Round 13
// baseline (75.061 us; speedup 1.0000x reference)
//
#include <hip/hip_runtime.h>
#include <hip/hip_bf16.h>
#include <stdint.h>

#define THRESH_FACTOR 0.05f
#define XCLIP 5.5f
#define QSTEP (XCLIP / 127.0f)

typedef __attribute__((ext_vector_type(4)))  int i32x4;
typedef __attribute__((ext_vector_type(16))) int i32x16;

// Chunk swizzle within each 8-chunk group (A only); yields the 4-lane/bank
// floor for 32-distinct-row b128 reads.
__device__ inline int swz_row(int r) { return (r & 7) ^ ((r >> 3) & 7); }

// ---------------- Kernel 1: per-row ternary quantization -> i8 (LINEAR) ----
__global__ void __launch_bounds__(256) quant_tern(
        const float* __restrict__ W, signed char* __restrict__ Wq,
        float* __restrict__ scale, int IN)
{
    const int row = blockIdx.x;
    const int tid = threadIdx.x;
    const int lane = tid & 63;
    const int wid = tid >> 6;
    const float4* wr4 = (const float4*)(W + (size_t)row * IN);
    const int n4 = IN >> 2;

    float s = 0.f;
    for (int i = tid; i < n4; i += 256) {
        float4 v = wr4[i];
        s += fabsf(v.x) + fabsf(v.y) + fabsf(v.z) + fabsf(v.w);
    }
    #pragma unroll
    for (int off = 32; off; off >>= 1) s += __shfl_down(s, off);
    __shared__ float redA[4], redB[4];
    if (lane == 0) redA[wid] = s;
    __syncthreads();
    const float delta = THRESH_FACTOR * (redA[0] + redA[1] + redA[2] + redA[3]) / (float)IN;
    __syncthreads();   // all delta-reads done before redA reuse

    float ks = 0.f, kn = 0.f;
    uint4* out16 = (uint4*)(Wq + (size_t)row * IN);   // 16B = 16 i8 chunks
    const int n16 = IN >> 4;                           // chunks per row
    for (int i = tid; i < n16; i += 256) {
        unsigned int wds[4] = {0u, 0u, 0u, 0u};
        #pragma unroll
        for (int j4 = 0; j4 < 4; ++j4) {
            float4 v = wr4[i * 4 + j4];
            float vs[4] = {v.x, v.y, v.z, v.w};
            unsigned int wd = 0;
            #pragma unroll
            for (int j = 0; j < 4; ++j) {
                float a = fabsf(vs[j]);
                unsigned int q = 0;
                if (a > delta) {
                    ks += a; kn += 1.f;
                    q = (__float_as_uint(vs[j]) >> 31) ? 0xFFu : 0x01u;  // -1 / +1
                }
                wd |= q << (8 * j);
            }
            wds[j4] = wd;
        }
        out16[i] = make_uint4(wds[0], wds[1], wds[2], wds[3]);   // linear
    }
    #pragma unroll
    for (int off = 32; off; off >>= 1) { ks += __shfl_down(ks, off); kn += __shfl_down(kn, off); }
    if (lane == 0) { redA[wid] = ks; redB[wid] = kn; }
    __syncthreads();
    if (tid == 0) {
        float tks = redA[0] + redA[1] + redA[2] + redA[3];
        float tkn = redB[0] + redB[1] + redB[2] + redB[3];
        scale[row] = tks / fmaxf(tkn, 1.f);
    }
}

// ---------------- Kernel 2: cast x (f32) -> i8, chunk-swizzled (A path) ----
__global__ void __launch_bounds__(256) cast_x(
        const float* __restrict__ X, signed char* __restrict__ Xq,
        int n16, int cshift)   // n16 = total 16-elem chunks; row = i >> cshift
{
    int idx = blockIdx.x * blockDim.x + threadIdx.x;
    int stride = gridDim.x * blockDim.x;
    const float4* x4 = (const float4*)X;
    uint4* o16 = (uint4*)Xq;
    const float inv = 1.0f / QSTEP;
    for (int i = idx; i < n16; i += stride) {
        int m = i >> cshift;                // source row
        unsigned int wds[4];
        #pragma unroll
        for (int j4 = 0; j4 < 4; ++j4) {
            float4 v = x4[i * 4 + j4];
            float vs[4] = {v.x, v.y, v.z, v.w};
            unsigned int wd = 0;
            #pragma unroll
            for (int j = 0; j < 4; ++j) {
                int q = __float2int_rn(fminf(fmaxf(vs[j] * inv, -127.f), 127.f));
                wd |= ((unsigned int)q & 0xFFu) << (8 * j);
            }
            wds[j4] = wd;
        }
        uint4 o = make_uint4(wds[0], wds[1], wds[2], wds[3]);
        const int oc = (i & ~7) | ((i & 7) ^ swz_row(m));   // chunk swizzle
        o16[oc] = o;
    }
}

// ---------------- Kernel 3: i8 MFMA GEMM, A-LDS / B-from-L2 -----------------
// C = (xq @ wq^T) * (QSTEP*scale[col]) + bias[col].  BM=BN=128, BK=128.
// 512 threads = 8 waves: 2x2 spatial x 2 K-groups. A: triple-buffered LDS
// (3x16KB), staged 2 steps ahead via global_load_lds. B: per-lane register
// gather from L2 (panel 512KB = XCD-L2-resident; half-wave pairs share 64B
// lines, wr-twin waves identical addrs -> L1), prefetched 1 step ahead.
// ONE barrier per step: barrier-at-top certifies step t-1 reads done before
// STAGE into buf (t+2)%3; vmcnt(10) = exact younger-op count for A-stage(t)
// (in-order vmcnt retirement). kg-merge via aliased LDS; f32 epilogue.
#define BM 128
#define BN 128
#define BK 128
#define THREADS 512

__global__ void __launch_bounds__(512, 1) gemm_tern(
        const signed char* __restrict__ Xq,   // [M][K] i8, swizzled chunks
        const signed char* __restrict__ Wq,   // [N][K] i8, LINEAR
        const float* __restrict__ scale,      // [N]
        const float* __restrict__ bias,       // [N]
        float* __restrict__ C,                // [M][N] f32
        int M, int N, int K)
{
    __shared__ __attribute__((aligned(16))) union SMem {
        signed char A[3][BM * BK];   // 48 KB
        int merge[4][4096];          // 64 KB
    } u;

    const int tid    = threadIdx.x;
    const int lane   = tid & 63;
    const int lane31 = lane & 31;
    const int khalf  = lane >> 5;
    const int wid    = tid >> 6;   // 0..7
    const int kg     = wid >> 2;   // K-group 0/1 (owns k[kg*64, kg*64+64))
    const int wq     = wid & 3;    // spatial wave id
    const int wr     = wq >> 1;    // 0..1 (M)
    const int wc     = wq & 1;     // 0..1 (N)

    // XCD-aware bijective swizzle (nwg=256, divisible by 8)
    const int nwg = gridDim.x;
    const int bid = blockIdx.x;
    const int swz = (bid & 7) * (nwg >> 3) + (bid >> 3);
    const int ntn = N / BN;                   // 8
    const int bm0 = (swz / ntn) * BM;
    const int bn0 = (swz % ntn) * BN;

    i32x16 acc[2][2];
    #pragma unroll
    for (int m = 0; m < 2; ++m)
        #pragma unroll
        for (int n = 0; n < 2; ++n)
            #pragma unroll
            for (int r = 0; r < 16; ++r)
                acc[m][n][r] = 0;

    const signed char* Ag = Xq + (size_t)bm0 * K;
    // B gather base: per-lane row (bn0 + wc*64 + lane31), frag (n,kk) adds
    // n*32 rows and picks 16B chunk (kg*4 + kk*2 + khalf) within the t-slice.
    const signed char* Bbase = Wq + (size_t)(bn0 + wc * 64 + lane31) * K;

    // A staging: tile = 128 rows x 8 chunks(16B) = 1024 slots; 2 calls/thread.
    const int spos = tid & 7;
    int srow[2];
    #pragma unroll
    for (int c = 0; c < 2; ++c) srow[c] = (c * THREADS + tid) >> 3;
    const int ldsb = (tid & ~63) * 16;   // byte base within call (+c*8192)

    #define STAGE(bi, t)                                                           \
        do {                                                                       \
            _Pragma("unroll")                                                      \
            for (int c = 0; c < 2; ++c) {                                          \
                __builtin_amdgcn_global_load_lds(                                  \
                    (const __attribute__((address_space(1))) unsigned int*)        \
                        (Ag + (size_t)srow[c] * K + (t) * 128 + spos * 16),        \
                    (__attribute__((address_space(3))) unsigned int*)              \
                        (&u.A[bi][c * 8192 + ldsb]),                               \
                    16, 0, 0);                                                     \
            }                                                                      \
        } while (0)

    #define LOADB(dst, t)                                                          \
        do {                                                                       \
            _Pragma("unroll")                                                      \
            for (int n = 0; n < 2; ++n)                                            \
                _Pragma("unroll")                                                  \
                for (int kk = 0; kk < 2; ++kk)                                     \
                    dst[n][kk] = *(const i32x4*)(Bbase + (size_t)n * 32 * K +      \
                        (size_t)(t) * 128 + (kg * 4 + kk * 2 + khalf) * 16);       \
        } while (0)

    const int NT = K / BK;             // 32
    const int rA0 = wr * 64 + lane31, rA1 = rA0 + 32;
    const int sA0 = swz_row(rA0), sA1 = swz_row(rA1);

    i32x4 bcur[2][2], bnxt[2][2];

    // ---- prologue: stage A(0)->buf0, A(1)->buf1; prefetch B(0) ----
    STAGE(0, 0);
    STAGE(1, 1);
    LOADB(bcur, 0);

    int bufR = 0, bufS = 2;

    for (int t = 0; t < NT; ++t) {
        if (t + 1 < NT) {
            LOADB(bnxt, t + 1);
            asm volatile("s_waitcnt vmcnt(10)" ::: "memory");  // A-stage(t) done
        } else {
            asm volatile("s_waitcnt vmcnt(4)" ::: "memory");   // only B(t) younger
        }
        __builtin_amdgcn_s_barrier();     // all waves: stage(t) landed, t-1 reads done

        if (t + 2 < NT) STAGE(bufS, t + 2);   // safe: everyone past step t-1

        const signed char* Ab = u.A[bufR];
        __builtin_amdgcn_s_setprio(1);
        #pragma unroll
        for (int kk = 0; kk < 2; ++kk) {
            const int c7 = kg * 4 + kk * 2 + khalf;   // logical chunk 0..7
            i32x4 a0 = *(const i32x4*)&Ab[rA0 * BK + ((c7 ^ sA0) * 16)];
            i32x4 a1 = *(const i32x4*)&Ab[rA1 * BK + ((c7 ^ sA1) * 16)];
            acc[0][0] = __builtin_amdgcn_mfma_i32_32x32x32_i8(a0, bcur[0][kk], acc[0][0], 0, 0, 0);
            acc[0][1] = __builtin_amdgcn_mfma_i32_32x32x32_i8(a0, bcur[1][kk], acc[0][1], 0, 0, 0);
            acc[1][0] = __builtin_amdgcn_mfma_i32_32x32x32_i8(a1, bcur[0][kk], acc[1][0], 0, 0, 0);
            acc[1][1] = __builtin_amdgcn_mfma_i32_32x32x32_i8(a1, bcur[1][kk], acc[1][1], 0, 0, 0);
        }
        __builtin_amdgcn_s_setprio(0);

        if (t + 1 < NT) {
            #pragma unroll
            for (int n = 0; n < 2; ++n)
                #pragma unroll
                for (int kk = 0; kk < 2; ++kk)
                    bcur[n][kk] = bnxt[n][kk];   // forces B(t+1) wait at step end
        }
        ++bufR; if (bufR == 3) bufR = 0;
        ++bufS; if (bufS == 3) bufS = 0;
    }

    __syncthreads();   // last step's A reads done before LDS reuse as merge

    // ---- K-group merge through LDS (aliases staging) ----
    if (kg == 1) {
        #pragma unroll
        for (int m = 0; m < 2; ++m)
            #pragma unroll
            for (int n = 0; n < 2; ++n)
                #pragma unroll
                for (int r = 0; r < 16; ++r)
                    u.merge[wq][((m * 2 + n) * 16 + r) * 64 + lane] = acc[m][n][r];
    }
    __syncthreads();
    if (kg == 0) {
        #pragma unroll
        for (int n = 0; n < 2; ++n) {
            int col = bn0 + wc * 64 + n * 32 + lane31;
            float fac = QSTEP * scale[col];
            float bs  = bias[col];
            #pragma unroll
            for (int m = 0; m < 2; ++m) {
                #pragma unroll
                for (int r = 0; r < 16; ++r) {
                    int v = acc[m][n][r] + u.merge[wq][((m * 2 + n) * 16 + r) * 64 + lane];
                    int row = bm0 + wr * 64 + m * 32 + (r & 3) + 8 * (r >> 2) + 4 * (lane >> 5);
                    C[(size_t)row * N + col] = (float)v * fac + bs;
                }
            }
        }
    }
    #undef STAGE
    #undef LOADB
}

extern "C" void kernel_launch(void* const* d_in, const int* in_sizes, int n_in,
                              void* d_out, int out_size, void* d_ws, size_t ws_size,
                              hipStream_t stream)
{
    const float* x    = (const float*)d_in[0];
    const float* w    = (const float*)d_in[1];
    const float* bias = (const float*)d_in[2];
    float* out = (float*)d_out;

    const int OUT = in_sizes[2];            // 1024
    const int IN  = in_sizes[1] / OUT;      // 4096
    const int B   = in_sizes[0] / IN;       // 4096

    // workspace layout: xq_i8 [B*IN] | wq_i8 [OUT*IN] | scale [OUT]
    signed char* Xq = (signed char*)d_ws;
    signed char* Wq = Xq + (size_t)B * IN;
    float* scale = (float*)(Wq + (size_t)OUT * IN);

    int cshift = 0;
    while ((1 << cshift) != (IN >> 4)) ++cshift;   // log2(chunks per row)

    quant_tern<<<OUT, 256, 0, stream>>>(w, Wq, scale, IN);
    cast_x<<<2048, 256, 0, stream>>>(x, Xq, (B * IN) >> 4, cshift);
    gemm_tern<<<dim3((B / BM) * (OUT / BN)), THREADS, 0, stream>>>(
        Xq, Wq, scale, bias, out, B, OUT, IN);
}

// Round 14
// 49.162 us; speedup vs baseline: 1.5268x; 1.5268x over previous
//
#include <hip/hip_runtime.h>
#include <hip/hip_bf16.h>
#include <stdint.h>

#define THRESH_FACTOR 0.05f
#define XCLIP 5.5f
#define QSTEP (XCLIP / 127.0f)

typedef __attribute__((ext_vector_type(4)))  int i32x4;
typedef __attribute__((ext_vector_type(16))) int i32x16;

// Chunk swizzle within each 8-chunk group; with 128B LDS rows this measured
// conflict-free (R7: SQ_LDS_BANK_CONFLICT = 0 at identical byte geometry).
__device__ inline int swz_row(int r) { return (r & 7) ^ ((r >> 3) & 7); }

// ---------------- Kernel 1: per-row ternary quantization -> i8 -------------
// w_tern in {-1,0,+1} exact i8, chunk-swizzled (16B chunks, 8-chunk groups);
// scale[row] = mean |w| over kept entries. Row cached in LDS during the
// |w|-sum pass -> W read from HBM ONCE (was twice).
__global__ void __launch_bounds__(256) quant_tern(
        const float* __restrict__ W, signed char* __restrict__ Wq,
        float* __restrict__ scale, int IN)
{
    __shared__ float4 rowc[1024];        // 16 KB row cache (IN = 4096 f32)
    __shared__ float redA[4], redB[4];

    const int row = blockIdx.x;
    const int tid = threadIdx.x;
    const int lane = tid & 63;
    const int wid = tid >> 6;
    const float4* wr4 = (const float4*)(W + (size_t)row * IN);
    const int n4 = IN >> 2;

    float s = 0.f;
    for (int i = tid; i < n4; i += 256) {
        float4 v = wr4[i];
        rowc[i] = v;                     // cache for pass 2
        s += fabsf(v.x) + fabsf(v.y) + fabsf(v.z) + fabsf(v.w);
    }
    #pragma unroll
    for (int off = 32; off; off >>= 1) s += __shfl_down(s, off);
    if (lane == 0) redA[wid] = s;
    __syncthreads();                     // also publishes rowc
    const float delta = THRESH_FACTOR * (redA[0] + redA[1] + redA[2] + redA[3]) / (float)IN;
    __syncthreads();                     // all delta-reads done before redA reuse

    const int sr = swz_row(row);
    float ks = 0.f, kn = 0.f;
    uint4* out16 = (uint4*)(Wq + (size_t)row * IN);   // 16B = 16 i8 chunks
    const int n16 = IN >> 4;                           // chunks per row (256)
    for (int i = tid; i < n16; i += 256) {
        unsigned int wds[4] = {0u, 0u, 0u, 0u};
        #pragma unroll
        for (int j4 = 0; j4 < 4; ++j4) {
            float4 v = rowc[i * 4 + j4];               // from LDS, not HBM
            float vs[4] = {v.x, v.y, v.z, v.w};
            unsigned int wd = 0;
            #pragma unroll
            for (int j = 0; j < 4; ++j) {
                float a = fabsf(vs[j]);
                unsigned int q = 0;
                if (a > delta) {
                    ks += a; kn += 1.f;
                    q = (__float_as_uint(vs[j]) >> 31) ? 0xFFu : 0x01u;  // -1 / +1
                }
                wd |= q << (8 * j);
            }
            wds[j4] = wd;
        }
        uint4 o = make_uint4(wds[0], wds[1], wds[2], wds[3]);
        const int oc = (i & ~7) | ((i & 7) ^ sr);   // chunk swizzle
        out16[oc] = o;
    }
    #pragma unroll
    for (int off = 32; off; off >>= 1) { ks += __shfl_down(ks, off); kn += __shfl_down(kn, off); }
    if (lane == 0) { redA[wid] = ks; redB[wid] = kn; }
    __syncthreads();
    if (tid == 0) {
        float tks = redA[0] + redA[1] + redA[2] + redA[3];
        float tkn = redB[0] + redB[1] + redB[2] + redB[3];
        scale[row] = tks / fmaxf(tkn, 1.f);
    }
}

// ---------------- Kernel 2: cast x (f32) -> i8, chunk-swizzled --------------
__global__ void __launch_bounds__(256) cast_x(
        const float* __restrict__ X, signed char* __restrict__ Xq,
        int n16, int cshift)   // n16 = total 16-elem chunks; row = i >> cshift
{
    int idx = blockIdx.x * blockDim.x + threadIdx.x;
    int stride = gridDim.x * blockDim.x;
    const float4* x4 = (const float4*)X;
    uint4* o16 = (uint4*)Xq;
    const float inv = 1.0f / QSTEP;
    for (int i = idx; i < n16; i += stride) {
        int m = i >> cshift;                // source row
        unsigned int wds[4];
        #pragma unroll
        for (int j4 = 0; j4 < 4; ++j4) {
            float4 v = x4[i * 4 + j4];
            float vs[4] = {v.x, v.y, v.z, v.w};
            unsigned int wd = 0;
            #pragma unroll
            for (int j = 0; j < 4; ++j) {
                int q = __float2int_rn(fminf(fmaxf(vs[j] * inv, -127.f), 127.f));
                wd |= ((unsigned int)q & 0xFFu) << (8 * j);
            }
            wds[j4] = wd;
        }
        uint4 o = make_uint4(wds[0], wds[1], wds[2], wds[3]);
        const int oc = (i & ~7) | ((i & 7) ^ swz_row(m));   // chunk swizzle
        o16[oc] = o;
    }
}

// ---------------- Kernel 3: i8 MFMA GEMM (R11, best measured) ---------------
// C = (xq @ wq^T) * (QSTEP*scale[col]) + bias[col].  BM=BN=128, BK=128.
// 512 threads = 8 waves: 2x2 spatial (wave 64x64, 2x2 frags of 32x32x32 i8)
// x 2 K-groups (kg owns K=64 of each step). Double-buffered LDS (64 KB),
// depth-2 counted-vmcnt pipeline via global_load_lds (producers pre-swizzle).
// Exact i32 accumulation; kg-merge via aliased LDS; f32 epilogue.
#define BM 128
#define BN 128
#define BK 128
#define THREADS 512

__global__ void __launch_bounds__(512, 2) gemm_tern(
        const signed char* __restrict__ Xq,   // [M][K] i8, swizzled
        const signed char* __restrict__ Wq,   // [N][K] i8, swizzled
        const float* __restrict__ scale,      // [N]
        const float* __restrict__ bias,       // [N]
        float* __restrict__ C,                // [M][N] f32
        int M, int N, int K)
{
    __shared__ __attribute__((aligned(16))) union SMem {
        struct { signed char A[2][BM * BK]; signed char B[2][BN * BK]; } s; // 64 KB
        int merge[4][64 * 64];                                              // 64 KB
    } u;

    const int tid    = threadIdx.x;
    const int lane   = tid & 63;
    const int lane31 = lane & 31;
    const int khalf  = lane >> 5;
    const int wid    = tid >> 6;   // 0..7
    const int kg     = wid >> 2;   // K-group 0/1 (owns k[kg*64, kg*64+64))
    const int wq     = wid & 3;    // spatial wave id
    const int wr     = wq >> 1;    // 0..1 (M)
    const int wc     = wq & 1;     // 0..1 (N)

    // XCD-aware bijective swizzle (nwg=256, divisible by 8)
    const int nwg = gridDim.x;
    const int bid = blockIdx.x;
    const int swz = (bid & 7) * (nwg >> 3) + (bid >> 3);
    const int ntn = N / BN;                   // 8
    const int bm0 = (swz / ntn) * BM;
    const int bn0 = (swz % ntn) * BN;

    i32x16 acc[2][2];
    #pragma unroll
    for (int m = 0; m < 2; ++m)
        #pragma unroll
        for (int n = 0; n < 2; ++n)
            #pragma unroll
            for (int r = 0; r < 16; ++r)
                acc[m][n][r] = 0;

    const signed char* Ag = Xq + (size_t)bm0 * K;
    const signed char* Bg = Wq + (size_t)bn0 * K;

    // staging: tile = 128 rows x 8 chunks(16B) = 1024 slots per matrix;
    // 512 threads -> 2 A + 2 B gload_lds per thread per step. Linear dest.
    const int spos = tid & 7;
    int srow[2];
    #pragma unroll
    for (int c = 0; c < 2; ++c) srow[c] = (c * THREADS + tid) >> 3;
    const int ldsb = (tid & ~63) * 16;   // byte base within call (+c*8192)

    #define STAGE(buf, t)                                                          \
        do {                                                                       \
            _Pragma("unroll")                                                      \
            for (int c = 0; c < 2; ++c) {                                          \
                __builtin_amdgcn_global_load_lds(                                  \
                    (const __attribute__((address_space(1))) unsigned int*)        \
                        (Ag + (size_t)srow[c] * K + (t) * 128 + spos * 16),        \
                    (__attribute__((address_space(3))) unsigned int*)              \
                        (&u.s.A[buf][c * 8192 + ldsb]),                            \
                    16, 0, 0);                                                     \
                __builtin_amdgcn_global_load_lds(                                  \
                    (const __attribute__((address_space(1))) unsigned int*)        \
                        (Bg + (size_t)srow[c] * K + (t) * 128 + spos * 16),        \
                    (__attribute__((address_space(3))) unsigned int*)              \
                        (&u.s.B[buf][c * 8192 + ldsb]),                            \
                    16, 0, 0);                                                     \
            }                                                                      \
        } while (0)

    const int NT = K / BK;             // 32
    const int rA0 = wr * 64 + lane31, rA1 = rA0 + 32;
    const int rB0 = wc * 64 + lane31, rB1 = rB0 + 32;
    const int sA0 = swz_row(rA0), sA1 = swz_row(rA1);
    const int sB0 = swz_row(rB0), sB1 = swz_row(rB1);

    STAGE(0, 0);
    int cur = 0;

    for (int t = 0; t < NT; ++t) {
        if (t + 1 < NT) {
            STAGE(cur ^ 1, t + 1);
            asm volatile("s_waitcnt vmcnt(4)" ::: "memory");  // my tile-t loads done
        } else {
            asm volatile("s_waitcnt vmcnt(0)" ::: "memory");
        }
        __builtin_amdgcn_s_barrier();                         // tile t staged (all)

        __builtin_amdgcn_s_setprio(1);
        #pragma unroll
        for (int kk = 0; kk < 2; ++kk) {
            // logical chunk 0..7: kg*4 + kk*2 + khalf (K = chunk*16 .. +16)
            const int c7 = kg * 4 + kk * 2 + khalf;
            i32x4 a0 = *(const i32x4*)&u.s.A[cur][rA0 * BK + ((c7 ^ sA0) * 16)];
            i32x4 a1 = *(const i32x4*)&u.s.A[cur][rA1 * BK + ((c7 ^ sA1) * 16)];
            i32x4 b0 = *(const i32x4*)&u.s.B[cur][rB0 * BK + ((c7 ^ sB0) * 16)];
            i32x4 b1 = *(const i32x4*)&u.s.B[cur][rB1 * BK + ((c7 ^ sB1) * 16)];
            acc[0][0] = __builtin_amdgcn_mfma_i32_32x32x32_i8(a0, b0, acc[0][0], 0, 0, 0);
            acc[0][1] = __builtin_amdgcn_mfma_i32_32x32x32_i8(a0, b1, acc[0][1], 0, 0, 0);
            acc[1][0] = __builtin_amdgcn_mfma_i32_32x32x32_i8(a1, b0, acc[1][0], 0, 0, 0);
            acc[1][1] = __builtin_amdgcn_mfma_i32_32x32x32_i8(a1, b1, acc[1][1], 0, 0, 0);
        }
        __builtin_amdgcn_s_setprio(0);
        __builtin_amdgcn_s_barrier();    // all reads of buf `cur` done before restage
        cur ^= 1;
    }

    // ---- K-group merge through LDS (aliases staging; loop fully barriered) ----
    if (kg == 1) {
        #pragma unroll
        for (int m = 0; m < 2; ++m)
            #pragma unroll
            for (int n = 0; n < 2; ++n)
                #pragma unroll
                for (int r = 0; r < 16; ++r)
                    u.merge[wq][((m * 2 + n) * 16 + r) * 64 + lane] = acc[m][n][r];
    }
    __syncthreads();
    if (kg == 0) {
        #pragma unroll
        for (int n = 0; n < 2; ++n) {
            int col = bn0 + wc * 64 + n * 32 + lane31;
            float fac = QSTEP * scale[col];
            float bs  = bias[col];
            #pragma unroll
            for (int m = 0; m < 2; ++m) {
                #pragma unroll
                for (int r = 0; r < 16; ++r) {
                    int v = acc[m][n][r] + u.merge[wq][((m * 2 + n) * 16 + r) * 64 + lane];
                    int row = bm0 + wr * 64 + m * 32 + (r & 3) + 8 * (r >> 2) + 4 * (lane >> 5);
                    C[(size_t)row * N + col] = (float)v * fac + bs;
                }
            }
        }
    }
    #undef STAGE
}

extern "C" void kernel_launch(void* const* d_in, const int* in_sizes, int n_in,
                              void* d_out, int out_size, void* d_ws, size_t ws_size,
                              hipStream_t stream)
{
    const float* x    = (const float*)d_in[0];
    const float* w    = (const float*)d_in[1];
    const float* bias = (const float*)d_in[2];
    float* out = (float*)d_out;

    const int OUT = in_sizes[2];            // 1024
    const int IN  = in_sizes[1] / OUT;      // 4096
    const int B   = in_sizes[0] / IN;       // 4096

    // workspace layout: xq_i8 [B*IN] | wq_i8 [OUT*IN] | scale [OUT]
    signed char* Xq = (signed char*)d_ws;
    signed char* Wq = Xq + (size_t)B * IN;
    float* scale = (float*)(Wq + (size_t)OUT * IN);

    int cshift = 0;
    while ((1 << cshift) != (IN >> 4)) ++cshift;   // log2(chunks per row)

    quant_tern<<<OUT, 256, 0, stream>>>(w, Wq, scale, IN);
    cast_x<<<2048, 256, 0, stream>>>(x, Xq, (B * IN) >> 4, cshift);
    gemm_tern<<<dim3((B / BM) * (OUT / BN)), THREADS, 0, stream>>>(
        Xq, Wq, scale, bias, out, B, OUT, IN);
}

// Round 15
// 46.628 us; speedup vs baseline: 1.6098x; 1.0543x over previous
//
#include <hip/hip_runtime.h>
#include <hip/hip_bf16.h>
#include <stdint.h>

#define THRESH_FACTOR 0.05f
#define XCLIP 5.5f
#define QSTEP (XCLIP / 127.0f)

typedef __attribute__((ext_vector_type(4)))  int i32x4;
typedef __attribute__((ext_vector_type(16))) int i32x16;

// Chunk swizzle within each 8-chunk group; with 128B LDS rows this measured
// conflict-free (R7: SQ_LDS_BANK_CONFLICT = 0 at identical byte geometry).
__device__ inline int swz_row(int r) { return (r & 7) ^ ((r >> 3) & 7); }

// ---------------- Kernel 1: fused prep = cast_x + quant_tern ---------------
// Blocks [0, 2048): x f32 -> i8 (clip 5.5, qstep 5.5/127), chunk-swizzled.
// Blocks [2048, 2048+OUT): one W row each -> ternary i8 (chunk-swizzled) +
// scale[row]; row cached in LDS so W is read from HBM once.
// Fusing removes one kernel boundary and lets the BW-bound cast fill the
// machine alongside quant's shorter pass.
__global__ void __launch_bounds__(256) prep(
        const float* __restrict__ X, const float* __restrict__ W,
        signed char* __restrict__ Xq, signed char* __restrict__ Wq,
        float* __restrict__ scale, int IN, int n16x, int cshift)
{
    __shared__ float4 rowc[1024];        // 16 KB row cache (quant path)
    __shared__ float redA[4], redB[4];

    const int tid = threadIdx.x;

    if (blockIdx.x < 2048) {
        // ---------------- cast_x path ----------------
        int idx = blockIdx.x * 256 + tid;
        int stride = 2048 * 256;
        const float4* x4 = (const float4*)X;
        uint4* o16 = (uint4*)Xq;
        const float inv = 1.0f / QSTEP;
        for (int i = idx; i < n16x; i += stride) {
            int m = i >> cshift;                // source row
            unsigned int wds[4];
            #pragma unroll
            for (int j4 = 0; j4 < 4; ++j4) {
                float4 v = x4[i * 4 + j4];
                float vs[4] = {v.x, v.y, v.z, v.w};
                unsigned int wd = 0;
                #pragma unroll
                for (int j = 0; j < 4; ++j) {
                    int q = __float2int_rn(fminf(fmaxf(vs[j] * inv, -127.f), 127.f));
                    wd |= ((unsigned int)q & 0xFFu) << (8 * j);
                }
                wds[j4] = wd;
            }
            uint4 o = make_uint4(wds[0], wds[1], wds[2], wds[3]);
            const int oc = (i & ~7) | ((i & 7) ^ swz_row(m));   // chunk swizzle
            o16[oc] = o;
        }
        return;
    }

    // ---------------- quant_tern path ----------------
    const int row = blockIdx.x - 2048;
    const int lane = tid & 63;
    const int wid = tid >> 6;
    const float4* wr4 = (const float4*)(W + (size_t)row * IN);
    const int n4 = IN >> 2;

    float s = 0.f;
    for (int i = tid; i < n4; i += 256) {
        float4 v = wr4[i];
        rowc[i] = v;                     // cache for pass 2
        s += fabsf(v.x) + fabsf(v.y) + fabsf(v.z) + fabsf(v.w);
    }
    #pragma unroll
    for (int off = 32; off; off >>= 1) s += __shfl_down(s, off);
    if (lane == 0) redA[wid] = s;
    __syncthreads();                     // also publishes rowc
    const float delta = THRESH_FACTOR * (redA[0] + redA[1] + redA[2] + redA[3]) / (float)IN;
    __syncthreads();                     // all delta-reads done before redA reuse

    const int sr = swz_row(row);
    float ks = 0.f, kn = 0.f;
    uint4* out16 = (uint4*)(Wq + (size_t)row * IN);   // 16B = 16 i8 chunks
    const int n16 = IN >> 4;                           // chunks per row
    for (int i = tid; i < n16; i += 256) {
        unsigned int wds[4] = {0u, 0u, 0u, 0u};
        #pragma unroll
        for (int j4 = 0; j4 < 4; ++j4) {
            float4 v = rowc[i * 4 + j4];               // from LDS, not HBM
            float vs[4] = {v.x, v.y, v.z, v.w};
            unsigned int wd = 0;
            #pragma unroll
            for (int j = 0; j < 4; ++j) {
                float a = fabsf(vs[j]);
                unsigned int q = 0;
                if (a > delta) {
                    ks += a; kn += 1.f;
                    q = (__float_as_uint(vs[j]) >> 31) ? 0xFFu : 0x01u;  // -1 / +1
                }
                wd |= q << (8 * j);
            }
            wds[j4] = wd;
        }
        uint4 o = make_uint4(wds[0], wds[1], wds[2], wds[3]);
        const int oc = (i & ~7) | ((i & 7) ^ sr);   // chunk swizzle
        out16[oc] = o;
    }
    #pragma unroll
    for (int off = 32; off; off >>= 1) { ks += __shfl_down(ks, off); kn += __shfl_down(kn, off); }
    if (lane == 0) { redA[wid] = ks; redB[wid] = kn; }
    __syncthreads();
    if (tid == 0) {
        float tks = redA[0] + redA[1] + redA[2] + redA[3];
        float tkn = redB[0] + redB[1] + redB[2] + redB[3];
        scale[row] = tks / fmaxf(tkn, 1.f);
    }
}

// ---------------- Kernel 2: i8 MFMA GEMM (R11, best measured) ---------------
// C = (xq @ wq^T) * (QSTEP*scale[col]) + bias[col].  BM=BN=128, BK=128.
// 512 threads = 8 waves: 2x2 spatial (wave 64x64, 2x2 frags of 32x32x32 i8)
// x 2 K-groups (kg owns K=64 of each step). Double-buffered LDS (64 KB),
// depth-2 counted-vmcnt pipeline via global_load_lds (producers pre-swizzle).
// Exact i32 accumulation; kg-merge via aliased LDS; f32 epilogue.
#define BM 128
#define BN 128
#define BK 128
#define THREADS 512

__global__ void __launch_bounds__(512, 2) gemm_tern(
        const signed char* __restrict__ Xq,   // [M][K] i8, swizzled
        const signed char* __restrict__ Wq,   // [N][K] i8, swizzled
        const float* __restrict__ scale,      // [N]
        const float* __restrict__ bias,       // [N]
        float* __restrict__ C,                // [M][N] f32
        int M, int N, int K)
{
    __shared__ __attribute__((aligned(16))) union SMem {
        struct { signed char A[2][BM * BK]; signed char B[2][BN * BK]; } s; // 64 KB
        int merge[4][64 * 64];                                              // 64 KB
    } u;

    const int tid    = threadIdx.x;
    const int lane   = tid & 63;
    const int lane31 = lane & 31;
    const int khalf  = lane >> 5;
    const int wid    = tid >> 6;   // 0..7
    const int kg     = wid >> 2;   // K-group 0/1 (owns k[kg*64, kg*64+64))
    const int wq     = wid & 3;    // spatial wave id
    const int wr     = wq >> 1;    // 0..1 (M)
    const int wc     = wq & 1;     // 0..1 (N)

    // XCD-aware bijective swizzle (nwg=256, divisible by 8)
    const int nwg = gridDim.x;
    const int bid = blockIdx.x;
    const int swz = (bid & 7) * (nwg >> 3) + (bid >> 3);
    const int ntn = N / BN;                   // 8
    const int bm0 = (swz / ntn) * BM;
    const int bn0 = (swz % ntn) * BN;

    i32x16 acc[2][2];
    #pragma unroll
    for (int m = 0; m < 2; ++m)
        #pragma unroll
        for (int n = 0; n < 2; ++n)
            #pragma unroll
            for (int r = 0; r < 16; ++r)
                acc[m][n][r] = 0;

    const signed char* Ag = Xq + (size_t)bm0 * K;
    const signed char* Bg = Wq + (size_t)bn0 * K;

    // staging: tile = 128 rows x 8 chunks(16B) = 1024 slots per matrix;
    // 512 threads -> 2 A + 2 B gload_lds per thread per step. Linear dest.
    const int spos = tid & 7;
    int srow[2];
    #pragma unroll
    for (int c = 0; c < 2; ++c) srow[c] = (c * THREADS + tid) >> 3;
    const int ldsb = (tid & ~63) * 16;   // byte base within call (+c*8192)

    #define STAGE(buf, t)                                                          \
        do {                                                                       \
            _Pragma("unroll")                                                      \
            for (int c = 0; c < 2; ++c) {                                          \
                __builtin_amdgcn_global_load_lds(                                  \
                    (const __attribute__((address_space(1))) unsigned int*)        \
                        (Ag + (size_t)srow[c] * K + (t) * 128 + spos * 16),        \
                    (__attribute__((address_space(3))) unsigned int*)              \
                        (&u.s.A[buf][c * 8192 + ldsb]),                            \
                    16, 0, 0);                                                     \
                __builtin_amdgcn_global_load_lds(                                  \
                    (const __attribute__((address_space(1))) unsigned int*)        \
                        (Bg + (size_t)srow[c] * K + (t) * 128 + spos * 16),        \
                    (__attribute__((address_space(3))) unsigned int*)              \
                        (&u.s.B[buf][c * 8192 + ldsb]),                            \
                    16, 0, 0);                                                     \
            }                                                                      \
        } while (0)

    const int NT = K / BK;             // 32
    const int rA0 = wr * 64 + lane31, rA1 = rA0 + 32;
    const int rB0 = wc * 64 + lane31, rB1 = rB0 + 32;
    const int sA0 = swz_row(rA0), sA1 = swz_row(rA1);
    const int sB0 = swz_row(rB0), sB1 = swz_row(rB1);

    STAGE(0, 0);
    int cur = 0;

    for (int t = 0; t < NT; ++t) {
        if (t + 1 < NT) {
            STAGE(cur ^ 1, t + 1);
            asm volatile("s_waitcnt vmcnt(4)" ::: "memory");  // my tile-t loads done
        } else {
            asm volatile("s_waitcnt vmcnt(0)" ::: "memory");
        }
        __builtin_amdgcn_s_barrier();                         // tile t staged (all)

        __builtin_amdgcn_s_setprio(1);
        #pragma unroll
        for (int kk = 0; kk < 2; ++kk) {
            // logical chunk 0..7: kg*4 + kk*2 + khalf (K = chunk*16 .. +16)
            const int c7 = kg * 4 + kk * 2 + khalf;
            i32x4 a0 = *(const i32x4*)&u.s.A[cur][rA0 * BK + ((c7 ^ sA0) * 16)];
            i32x4 a1 = *(const i32x4*)&u.s.A[cur][rA1 * BK + ((c7 ^ sA1) * 16)];
            i32x4 b0 = *(const i32x4*)&u.s.B[cur][rB0 * BK + ((c7 ^ sB0) * 16)];
            i32x4 b1 = *(const i32x4*)&u.s.B[cur][rB1 * BK + ((c7 ^ sB1) * 16)];
            acc[0][0] = __builtin_amdgcn_mfma_i32_32x32x32_i8(a0, b0, acc[0][0], 0, 0, 0);
            acc[0][1] = __builtin_amdgcn_mfma_i32_32x32x32_i8(a0, b1, acc[0][1], 0, 0, 0);
            acc[1][0] = __builtin_amdgcn_mfma_i32_32x32x32_i8(a1, b0, acc[1][0], 0, 0, 0);
            acc[1][1] = __builtin_amdgcn_mfma_i32_32x32x32_i8(a1, b1, acc[1][1], 0, 0, 0);
        }
        __builtin_amdgcn_s_setprio(0);
        __builtin_amdgcn_s_barrier();    // all reads of buf `cur` done before restage
        cur ^= 1;
    }

    // ---- K-group merge through LDS (aliases staging; loop fully barriered) ----
    if (kg == 1) {
        #pragma unroll
        for (int m = 0; m < 2; ++m)
            #pragma unroll
            for (int n = 0; n < 2; ++n)
                #pragma unroll
                for (int r = 0; r < 16; ++r)
                    u.merge[wq][((m * 2 + n) * 16 + r) * 64 + lane] = acc[m][n][r];
    }
    __syncthreads();
    if (kg == 0) {
        #pragma unroll
        for (int n = 0; n < 2; ++n) {
            int col = bn0 + wc * 64 + n * 32 + lane31;
            float fac = QSTEP * scale[col];
            float bs  = bias[col];
            #pragma unroll
            for (int m = 0; m < 2; ++m) {
                #pragma unroll
                for (int r = 0; r < 16; ++r) {
                    int v = acc[m][n][r] + u.merge[wq][((m * 2 + n) * 16 + r) * 64 + lane];
                    int row = bm0 + wr * 64 + m * 32 + (r & 3) + 8 * (r >> 2) + 4 * (lane >> 5);
                    C[(size_t)row * N + col] = (float)v * fac + bs;
                }
            }
        }
    }
    #undef STAGE
}

extern "C" void kernel_launch(void* const* d_in, const int* in_sizes, int n_in,
                              void* d_out, int out_size, void* d_ws, size_t ws_size,
                              hipStream_t stream)
{
    const float* x    = (const float*)d_in[0];
    const float* w    = (const float*)d_in[1];
    const float* bias = (const float*)d_in[2];
    float* out = (float*)d_out;

    const int OUT = in_sizes[2];            // 1024
    const int IN  = in_sizes[1] / OUT;      // 4096
    const int B   = in_sizes[0] / IN;       // 4096

    // workspace layout: xq_i8 [B*IN] | wq_i8 [OUT*IN] | scale [OUT]
    signed char* Xq = (signed char*)d_ws;
    signed char* Wq = Xq + (size_t)B * IN;
    float* scale = (float*)(Wq + (size_t)OUT * IN);

    int cshift = 0;
    while ((1 << cshift) != (IN >> 4)) ++cshift;   // log2(chunks per row)

    prep<<<2048 + OUT, 256, 0, stream>>>(x, w, Xq, Wq, scale, IN, (B * IN) >> 4, cshift);
    gemm_tern<<<dim3((B / BM) * (OUT / BN)), THREADS, 0, stream>>>(
        Xq, Wq, scale, bias, out, B, OUT, IN);
}

// Round 16
// 44.321 us; speedup vs baseline: 1.6936x; 1.0521x over previous
//
#include <hip/hip_runtime.h>
#include <hip/hip_bf16.h>
#include <stdint.h>

#define THRESH_FACTOR 0.05f
#define XCLIP 5.5f
#define QSTEP (XCLIP / 127.0f)

typedef __attribute__((ext_vector_type(4)))  int i32x4;
typedef __attribute__((ext_vector_type(16))) int i32x16;

// Chunk swizzle within each 8-chunk group; with 128B LDS rows this measured
// conflict-free (R7: SQ_LDS_BANK_CONFLICT = 0 at identical byte geometry).
__device__ inline int swz_row(int r) { return (r & 7) ^ ((r >> 3) & 7); }

// ---------------- Kernel 1: fused prep = cast_x + quant_tern ---------------
// Blocks [0, 2048): x f32 -> i8 (clip 5.5, qstep 5.5/127), chunk-swizzled.
// Blocks [2048, 2048+OUT): one W row each -> ternary i8 (chunk-swizzled) +
// scale[row]; row cached in LDS so W is read from HBM once.
__global__ void __launch_bounds__(256) prep(
        const float* __restrict__ X, const float* __restrict__ W,
        signed char* __restrict__ Xq, signed char* __restrict__ Wq,
        float* __restrict__ scale, int IN, int n16x, int cshift)
{
    __shared__ float4 rowc[1024];        // 16 KB row cache (quant path)
    __shared__ float redA[4], redB[4];

    const int tid = threadIdx.x;

    if (blockIdx.x < 2048) {
        // ---------------- cast_x path ----------------
        int idx = blockIdx.x * 256 + tid;
        int stride = 2048 * 256;
        const float4* x4 = (const float4*)X;
        uint4* o16 = (uint4*)Xq;
        const float inv = 1.0f / QSTEP;
        for (int i = idx; i < n16x; i += stride) {
            int m = i >> cshift;                // source row
            unsigned int wds[4];
            #pragma unroll
            for (int j4 = 0; j4 < 4; ++j4) {
                float4 v = x4[i * 4 + j4];
                float vs[4] = {v.x, v.y, v.z, v.w};
                unsigned int wd = 0;
                #pragma unroll
                for (int j = 0; j < 4; ++j) {
                    int q = __float2int_rn(fminf(fmaxf(vs[j] * inv, -127.f), 127.f));
                    wd |= ((unsigned int)q & 0xFFu) << (8 * j);
                }
                wds[j4] = wd;
            }
            uint4 o = make_uint4(wds[0], wds[1], wds[2], wds[3]);
            const int oc = (i & ~7) | ((i & 7) ^ swz_row(m));   // chunk swizzle
            o16[oc] = o;
        }
        return;
    }

    // ---------------- quant_tern path ----------------
    const int row = blockIdx.x - 2048;
    const int lane = tid & 63;
    const int wid = tid >> 6;
    const float4* wr4 = (const float4*)(W + (size_t)row * IN);
    const int n4 = IN >> 2;

    float s = 0.f;
    for (int i = tid; i < n4; i += 256) {
        float4 v = wr4[i];
        rowc[i] = v;                     // cache for pass 2
        s += fabsf(v.x) + fabsf(v.y) + fabsf(v.z) + fabsf(v.w);
    }
    #pragma unroll
    for (int off = 32; off; off >>= 1) s += __shfl_down(s, off);
    if (lane == 0) redA[wid] = s;
    __syncthreads();                     // also publishes rowc
    const float delta = THRESH_FACTOR * (redA[0] + redA[1] + redA[2] + redA[3]) / (float)IN;
    __syncthreads();                     // all delta-reads done before redA reuse

    const int sr = swz_row(row);
    float ks = 0.f, kn = 0.f;
    uint4* out16 = (uint4*)(Wq + (size_t)row * IN);   // 16B = 16 i8 chunks
    const int n16 = IN >> 4;                           // chunks per row
    for (int i = tid; i < n16; i += 256) {
        unsigned int wds[4] = {0u, 0u, 0u, 0u};
        #pragma unroll
        for (int j4 = 0; j4 < 4; ++j4) {
            float4 v = rowc[i * 4 + j4];               // from LDS, not HBM
            float vs[4] = {v.x, v.y, v.z, v.w};
            unsigned int wd = 0;
            #pragma unroll
            for (int j = 0; j < 4; ++j) {
                float a = fabsf(vs[j]);
                unsigned int q = 0;
                if (a > delta) {
                    ks += a; kn += 1.f;
                    q = (__float_as_uint(vs[j]) >> 31) ? 0xFFu : 0x01u;  // -1 / +1
                }
                wd |= q << (8 * j);
            }
            wds[j4] = wd;
        }
        uint4 o = make_uint4(wds[0], wds[1], wds[2], wds[3]);
        const int oc = (i & ~7) | ((i & 7) ^ sr);   // chunk swizzle
        out16[oc] = o;
    }
    #pragma unroll
    for (int off = 32; off; off >>= 1) { ks += __shfl_down(ks, off); kn += __shfl_down(kn, off); }
    if (lane == 0) { redA[wid] = ks; redB[wid] = kn; }
    __syncthreads();
    if (tid == 0) {
        float tks = redA[0] + redA[1] + redA[2] + redA[3];
        float tkn = redB[0] + redB[1] + redB[2] + redB[3];
        scale[row] = tks / fmaxf(tkn, 1.f);
    }
}

// ---------------- Kernel 2: i8 MFMA GEMM, phase-split inner loop ------------
// C = (xq @ wq^T) * (QSTEP*scale[col]) + bias[col].  BM=BN=128, BK=128.
// 512 threads = 8 waves: 2x2 spatial x 2 K-groups (R11 geometry verbatim).
// CHANGE vs R11 (the one lever under test): per step, the 8-read/8-MFMA blobs
// are split into 2 phases {4 ds_read(kk) || 2 gload_lds -> barrier ->
// setprio 4xMFMA}, reads hoisted BEFORE the barrier so barrier-skew staggers
// waves across the DS and matrix pipes instead of serializing them.
// Triple-buffered LDS (3x32 KB) gives WAR slack; ONE counted vmcnt(4) gate
// per step (tile t+1 landed by in-order retirement; never 0 mid-loop).
// Barrier count per step unchanged (2).
#define BM 128
#define BN 128
#define BK 128
#define THREADS 512

__global__ void __launch_bounds__(512, 1) gemm_tern(
        const signed char* __restrict__ Xq,   // [M][K] i8, swizzled
        const signed char* __restrict__ Wq,   // [N][K] i8, swizzled
        const float* __restrict__ scale,      // [N]
        const float* __restrict__ bias,       // [N]
        float* __restrict__ C,                // [M][N] f32
        int M, int N, int K)
{
    __shared__ __attribute__((aligned(16))) union SMem {
        struct { signed char A[3][BM * BK]; signed char B[3][BN * BK]; } s; // 96 KB
        int merge[4][4096];                                                 // 64 KB
    } u;

    const int tid    = threadIdx.x;
    const int lane   = tid & 63;
    const int lane31 = lane & 31;
    const int khalf  = lane >> 5;
    const int wid    = tid >> 6;   // 0..7
    const int kg     = wid >> 2;   // K-group 0/1 (owns k[kg*64, kg*64+64))
    const int wq     = wid & 3;    // spatial wave id
    const int wr     = wq >> 1;    // 0..1 (M)
    const int wc     = wq & 1;     // 0..1 (N)

    // XCD-aware bijective swizzle (nwg=256, divisible by 8)
    const int nwg = gridDim.x;
    const int bid = blockIdx.x;
    const int swz = (bid & 7) * (nwg >> 3) + (bid >> 3);
    const int ntn = N / BN;                   // 8
    const int bm0 = (swz / ntn) * BM;
    const int bn0 = (swz % ntn) * BN;

    i32x16 acc[2][2];
    #pragma unroll
    for (int m = 0; m < 2; ++m)
        #pragma unroll
        for (int n = 0; n < 2; ++n)
            #pragma unroll
            for (int r = 0; r < 16; ++r)
                acc[m][n][r] = 0;

    const signed char* Ag = Xq + (size_t)bm0 * K;
    const signed char* Bg = Wq + (size_t)bn0 * K;

    // staging: tile = 128 rows x 8 chunks(16B) = 1024 slots per matrix;
    // 512 threads -> 2 A + 2 B gload_lds per thread per step. Linear dest.
    const int spos = tid & 7;
    int srow[2];
    #pragma unroll
    for (int c = 0; c < 2; ++c) srow[c] = (c * THREADS + tid) >> 3;
    const int ldsb = (tid & ~63) * 16;   // byte base within call (+c*8192)

    #define STAGE_A(bi, t)                                                         \
        do {                                                                       \
            _Pragma("unroll")                                                      \
            for (int c = 0; c < 2; ++c) {                                          \
                __builtin_amdgcn_global_load_lds(                                  \
                    (const __attribute__((address_space(1))) unsigned int*)        \
                        (Ag + (size_t)srow[c] * K + (t) * 128 + spos * 16),        \
                    (__attribute__((address_space(3))) unsigned int*)              \
                        (&u.s.A[bi][c * 8192 + ldsb]),                             \
                    16, 0, 0);                                                     \
            }                                                                      \
        } while (0)
    #define STAGE_B(bi, t)                                                         \
        do {                                                                       \
            _Pragma("unroll")                                                      \
            for (int c = 0; c < 2; ++c) {                                          \
                __builtin_amdgcn_global_load_lds(                                  \
                    (const __attribute__((address_space(1))) unsigned int*)        \
                        (Bg + (size_t)srow[c] * K + (t) * 128 + spos * 16),        \
                    (__attribute__((address_space(3))) unsigned int*)              \
                        (&u.s.B[bi][c * 8192 + ldsb]),                             \
                    16, 0, 0);                                                     \
            }                                                                      \
        } while (0)

    const int NT = K / BK;             // 32
    const int rA0 = wr * 64 + lane31, rA1 = rA0 + 32;
    const int rB0 = wc * 64 + lane31, rB1 = rB0 + 32;
    const int sA0 = swz_row(rA0), sA1 = swz_row(rA1);
    const int sB0 = swz_row(rB0), sB1 = swz_row(rB1);

    // ---- prologue: stage tile0 -> buf0, tile1 -> buf1; gate tile0 ----
    STAGE_A(0, 0); STAGE_B(0, 0);
    STAGE_A(1, 1); STAGE_B(1, 1);
    asm volatile("s_waitcnt vmcnt(4)" ::: "memory");   // tile0 landed; tile1 in flight
    __builtin_amdgcn_s_barrier();

    int bR = 0, bS = 2;

    for (int t = 0; t < NT; ++t) {
        const bool st = (t + 2 < NT);
        const signed char* Ab = u.s.A[bR];
        const signed char* Bb = u.s.B[bR];

        // ---- phase 0 (kk=0): reads before barrier; stage A-half ----
        {
            const int c7 = kg * 4 + khalf;              // kk=0
            i32x4 a0 = *(const i32x4*)&Ab[rA0 * BK + ((c7 ^ sA0) * 16)];
            i32x4 a1 = *(const i32x4*)&Ab[rA1 * BK + ((c7 ^ sA1) * 16)];
            i32x4 b0 = *(const i32x4*)&Bb[rB0 * BK + ((c7 ^ sB0) * 16)];
            i32x4 b1 = *(const i32x4*)&Bb[rB1 * BK + ((c7 ^ sB1) * 16)];
            if (st) STAGE_A(bS, t + 2);
            __builtin_amdgcn_s_barrier();
            __builtin_amdgcn_s_setprio(1);
            acc[0][0] = __builtin_amdgcn_mfma_i32_32x32x32_i8(a0, b0, acc[0][0], 0, 0, 0);
            acc[0][1] = __builtin_amdgcn_mfma_i32_32x32x32_i8(a0, b1, acc[0][1], 0, 0, 0);
            acc[1][0] = __builtin_amdgcn_mfma_i32_32x32x32_i8(a1, b0, acc[1][0], 0, 0, 0);
            acc[1][1] = __builtin_amdgcn_mfma_i32_32x32x32_i8(a1, b1, acc[1][1], 0, 0, 0);
            __builtin_amdgcn_s_setprio(0);
        }

        // ---- phase 1 (kk=1): reads; stage B-half; counted gate for tile t+1 --
        {
            const int c7 = kg * 4 + 2 + khalf;          // kk=1
            i32x4 a0 = *(const i32x4*)&Ab[rA0 * BK + ((c7 ^ sA0) * 16)];
            i32x4 a1 = *(const i32x4*)&Ab[rA1 * BK + ((c7 ^ sA1) * 16)];
            i32x4 b0 = *(const i32x4*)&Bb[rB0 * BK + ((c7 ^ sB0) * 16)];
            i32x4 b1 = *(const i32x4*)&Bb[rB1 * BK + ((c7 ^ sB1) * 16)];
            if (st) {
                STAGE_B(bS, t + 2);
                asm volatile("s_waitcnt vmcnt(4)" ::: "memory");  // tile t+1 landed
            } else {
                asm volatile("s_waitcnt vmcnt(0)" ::: "memory");  // drain tail
            }
            __builtin_amdgcn_s_barrier();
            __builtin_amdgcn_s_setprio(1);
            acc[0][0] = __builtin_amdgcn_mfma_i32_32x32x32_i8(a0, b0, acc[0][0], 0, 0, 0);
            acc[0][1] = __builtin_amdgcn_mfma_i32_32x32x32_i8(a0, b1, acc[0][1], 0, 0, 0);
            acc[1][0] = __builtin_amdgcn_mfma_i32_32x32x32_i8(a1, b0, acc[1][0], 0, 0, 0);
            acc[1][1] = __builtin_amdgcn_mfma_i32_32x32x32_i8(a1, b1, acc[1][1], 0, 0, 0);
            __builtin_amdgcn_s_setprio(0);
        }

        ++bR; if (bR == 3) bR = 0;
        ++bS; if (bS == 3) bS = 0;
    }

    __syncthreads();   // last tile's reads done before LDS reuse as merge

    // ---- K-group merge through LDS (aliases staging) ----
    if (kg == 1) {
        #pragma unroll
        for (int m = 0; m < 2; ++m)
            #pragma unroll
            for (int n = 0; n < 2; ++n)
                #pragma unroll
                for (int r = 0; r < 16; ++r)
                    u.merge[wq][((m * 2 + n) * 16 + r) * 64 + lane] = acc[m][n][r];
    }
    __syncthreads();
    if (kg == 0) {
        #pragma unroll
        for (int n = 0; n < 2; ++n) {
            int col = bn0 + wc * 64 + n * 32 + lane31;
            float fac = QSTEP * scale[col];
            float bs  = bias[col];
            #pragma unroll
            for (int m = 0; m < 2; ++m) {
                #pragma unroll
                for (int r = 0; r < 16; ++r) {
                    int v = acc[m][n][r] + u.merge[wq][((m * 2 + n) * 16 + r) * 64 + lane];
                    int row = bm0 + wr * 64 + m * 32 + (r & 3) + 8 * (r >> 2) + 4 * (lane >> 5);
                    C[(size_t)row * N + col] = (float)v * fac + bs;
                }
            }
        }
    }
    #undef STAGE_A
    #undef STAGE_B
}

extern "C" void kernel_launch(void* const* d_in, const int* in_sizes, int n_in,
                              void* d_out, int out_size, void* d_ws, size_t ws_size,
                              hipStream_t stream)
{
    const float* x    = (const float*)d_in[0];
    const float* w    = (const float*)d_in[1];
    const float* bias = (const float*)d_in[2];
    float* out = (float*)d_out;

    const int OUT = in_sizes[2];            // 1024
    const int IN  = in_sizes[1] / OUT;      // 4096
    const int B   = in_sizes[0] / IN;       // 4096

    // workspace layout: xq_i8 [B*IN] | wq_i8 [OUT*IN] | scale [OUT]
    signed char* Xq = (signed char*)d_ws;
    signed char* Wq = Xq + (size_t)B * IN;
    float* scale = (float*)(Wq + (size_t)OUT * IN);

    int cshift = 0;
    while ((1 << cshift) != (IN >> 4)) ++cshift;   // log2(chunks per row)

    prep<<<2048 + OUT, 256, 0, stream>>>(x, w, Xq, Wq, scale, IN, (B * IN) >> 4, cshift);
    gemm_tern<<<dim3((B / BM) * (OUT / BN)), THREADS, 0, stream>>>(
        Xq, Wq, scale, bias, out, B, OUT, IN);
}